// Round 10
// baseline (825.474 us; speedup 1.0000x reference)
//
#include <hip/hip_runtime.h>
#include <hip/hip_bf16.h>
#include <math.h>

#define DM 768
#define NH 12
#define HD 64
#define B_ 4
#define SQ_ 1024
#define SK_ 2048
#define QT 16

typedef __bf16 bf16x8 __attribute__((ext_vector_type(8)));
typedef __bf16 bf16x4 __attribute__((ext_vector_type(4)));
typedef float f32x4 __attribute__((ext_vector_type(4)));

static __device__ __forceinline__ f32x4 mfma16(bf16x8 a, bf16x8 b, f32x4 c) {
    return __builtin_amdgcn_mfma_f32_16x16x32_bf16(a, b, c, 0, 0, 0);
}

// ---------------- block reductions (256 threads, 4 waves of 64) ----------------
__device__ __forceinline__ float blksum(float v, float* rb, int tid) {
#pragma unroll
    for (int off = 32; off; off >>= 1) v += __shfl_down(v, off, 64);
    if ((tid & 63) == 0) rb[tid >> 6] = v;
    __syncthreads();
    if (tid == 0) rb[4] = rb[0] + rb[1] + rb[2] + rb[3];
    __syncthreads();
    return rb[4];
}

// ---------------- W transpose + cast: Wt[n][k] bf16 from W[k][n] fp32 (4x) -----
__global__ __launch_bounds__(256)
void transpose_cast4(const float* __restrict__ W0, const float* __restrict__ W1,
                     const float* __restrict__ W2, const float* __restrict__ W3,
                     __hip_bfloat16* __restrict__ T0, __hip_bfloat16* __restrict__ T1,
                     __hip_bfloat16* __restrict__ T2, __hip_bfloat16* __restrict__ T3)
{
    __shared__ float Ls[64][68];
    const int z = blockIdx.z;
    const float* W = (z == 0) ? W0 : (z == 1) ? W1 : (z == 2) ? W2 : W3;
    __hip_bfloat16* T = (z == 0) ? T0 : (z == 1) ? T1 : (z == 2) ? T2 : T3;
    const int k0 = blockIdx.y * 64, n0 = blockIdx.x * 64;
    const int tid = threadIdx.x;
    const int kl = tid >> 4, n4 = (tid & 15) * 4;
#pragma unroll
    for (int p = 0; p < 4; ++p) {
        float4 v = *(const float4*)&W[(size_t)(k0 + kl + p * 16) * DM + n0 + n4];
        *(float4*)&Ls[kl + p * 16][n4] = v;
    }
    __syncthreads();
    const int nl = tid >> 2, kq = (tid & 3) * 16;
    __hip_bfloat16 tmp[16];
#pragma unroll
    for (int i = 0; i < 16; ++i) tmp[i] = __float2bfloat16(Ls[kq + i][nl]);
    *(bf16x8*)&T[(size_t)(n0 + nl) * DM + k0 + kq]     = *(bf16x8*)&tmp[0];
    *(bf16x8*)&T[(size_t)(n0 + nl) * DM + k0 + kq + 8] = *(bf16x8*)&tmp[8];
}

// ---------------- fp32 -> bf16 cast ------------------------------------------
__device__ __forceinline__ void cast_body(const float* __restrict__ X,
                                          __hip_bfloat16* __restrict__ Xh, int i)
{
    float4 v = ((const float4*)X)[i];
    float xs[4] = {v.x, v.y, v.z, v.w};
    bf16x4 h;
#pragma unroll
    for (int e = 0; e < 4; ++e) h[e] = (__bf16)xs[e];
    *(bf16x4*)&Xh[(size_t)i * 4] = h;
}

// fused q/k/v cast: blocks [0,3072) q, [3072,9216) k, [9216,15360) v
__global__ __launch_bounds__(256)
void cast3_bf16(const float* __restrict__ q, const float* __restrict__ k,
                const float* __restrict__ v,
                __hip_bfloat16* __restrict__ qh, __hip_bfloat16* __restrict__ kh,
                __hip_bfloat16* __restrict__ vh)
{
    const int b = blockIdx.x;
    const float* X; __hip_bfloat16* H; int base;
    if (b < 3072)      { X = q; H = qh; base = b; }
    else if (b < 9216) { X = k; H = kh; base = b - 3072; }
    else               { X = v; H = vh; base = b - 9216; }
    cast_body(X, H, base * 256 + threadIdx.x);
}

// ---------------- barrier-free direct GEMM -------------------------------------
// C[32 x 128] per block = A[32 x 768] @ Wt^T, A,Wt bf16 read DIRECTLY from
// global (L2-resident: W=1.1MB, A panels hot). No LDS, no barriers: the K-loop
// is pure {4x b128 load, 4x MFMA} fully compiler-pipelined.
// Wave w owns cols [w*32, w*32+32). NI=NJ=2 16x16 frags, K-step 32, 24 steps.
// MODE 0: bf16 head-split; MODE 1: fp32 + bias + resid; MODE 2: bf16 transposed.
template <int MODE>
__device__ __forceinline__ void gemm_direct(
    const __hip_bfloat16* __restrict__ A, const __hip_bfloat16* __restrict__ Wt,
    float* __restrict__ outf, __hip_bfloat16* __restrict__ outb, int S,
    const float* __restrict__ bias, const float* __restrict__ resid, int lbid)
{
    const int tid  = threadIdx.x;
    const int lane = tid & 63;
    const int w    = tid >> 6;
    const int l16  = lane & 15;
    const int lq   = lane >> 4;

    const int bn = lbid % (DM / 128);
    const int bm = lbid / (DM / 128);
    const int row0 = bm * 32;
    const int col0 = bn * 128 + w * 32;

    const __hip_bfloat16* arow = A  + (size_t)(row0 + l16) * DM + lq * 8;
    const __hip_bfloat16* wrow = Wt + (size_t)(col0 + l16) * DM + lq * 8;

    f32x4 acc[2][2] = {};
#pragma unroll 4
    for (int c = 0; c < DM / 32; ++c) {
        const int k = c * 32;
        const bf16x8 a0 = *(const bf16x8*)&arow[k];
        const bf16x8 a1 = *(const bf16x8*)&arow[(size_t)16 * DM + k];
        const bf16x8 w0 = *(const bf16x8*)&wrow[k];
        const bf16x8 w1 = *(const bf16x8*)&wrow[(size_t)16 * DM + k];
        acc[0][0] = mfma16(a0, w0, acc[0][0]);
        acc[0][1] = mfma16(a0, w1, acc[0][1]);
        acc[1][0] = mfma16(a1, w0, acc[1][0]);
        acc[1][1] = mfma16(a1, w1, acc[1][1]);
    }

    // row = row0 + i*16 + lq*4 + rr, col = col0 + j*16 + l16
    int b_blk = 0, s_base = 0;
    if (MODE != 1) {
        b_blk  = row0 / S;
        s_base = row0 - b_blk * S;
    }
#pragma unroll
    for (int i = 0; i < 2; ++i) {
#pragma unroll
        for (int j = 0; j < 2; ++j) {
#pragma unroll
            for (int rr = 0; rr < 4; ++rr) {
                const int cc = col0 + j * 16 + l16;
                if (MODE == 1) {
                    const int r = row0 + i * 16 + lq * 4 + rr;
                    outf[(size_t)r * DM + cc] =
                        acc[i][j][rr] + bias[cc] + resid[(size_t)r * DM + cc];
                } else {
                    const int s  = s_base + i * 16 + lq * 4 + rr;
                    const int h  = cc >> 6, hd = cc & 63;
                    if (MODE == 0)
                        outb[(((size_t)b_blk * NH + h) * S + s) * HD + hd] =
                            __float2bfloat16(acc[i][j][rr]);
                    else
                        outb[(((size_t)b_blk * NH + h) * HD + hd) * S + s] =
                            __float2bfloat16(acc[i][j][rr]);
                }
            }
        }
    }
}

// fused QKV projection, XCD-chunked (3840 = 8*480):
// lbid [0,768) Q, [768,2304) K, [2304,3840) V
__global__ __launch_bounds__(256)
void gemm_qkv(const __hip_bfloat16* __restrict__ qh, const __hip_bfloat16* __restrict__ kh,
              const __hip_bfloat16* __restrict__ vh,
              const __hip_bfloat16* __restrict__ Wqt, const __hip_bfloat16* __restrict__ Wkt,
              const __hip_bfloat16* __restrict__ Wvt,
              __hip_bfloat16* __restrict__ Qb, __hip_bfloat16* __restrict__ Kb,
              __hip_bfloat16* __restrict__ Vt)
{
    const int bid  = blockIdx.x;
    const int lbid = (bid & 7) * 480 + (bid >> 3);
    if (lbid < 768)
        gemm_direct<0>(qh, Wqt, nullptr, Qb, SQ_, nullptr, nullptr, lbid);
    else if (lbid < 2304)
        gemm_direct<0>(kh, Wkt, nullptr, Kb, SK_, nullptr, nullptr, lbid - 768);
    else
        gemm_direct<2>(vh, Wvt, nullptr, Vt, SK_, nullptr, nullptr, lbid - 2304);
}

// O projection (768 = 8*96): bf16 ctx @ Wo + bias + residual -> fp32
__global__ __launch_bounds__(256)
void gemm_o(const __hip_bfloat16* __restrict__ a, const __hip_bfloat16* __restrict__ Wot,
            float* __restrict__ outf, const float* __restrict__ bias,
            const float* __restrict__ resid)
{
    const int bid  = blockIdx.x;
    const int lbid = (bid & 7) * 96 + (bid >> 3);
    gemm_direct<1>(a, Wot, outf, nullptr, SQ_, bias, resid, lbid);
}

// ---------------- flash attention, p held in registers -------------------------
// Sweep 1: QK^T + exp; p packed to bf16 pairs in 64 VGPRs; row-sums in regs.
// Sweep 2: unpack+normalize into per-wave fp32 ftile[16][33]; every 2 tiles each
// lane reads back its PV fragment row (float4 x2, <=2-way banks), writes attn as
// coalesced float4 x2 (full fp32), converts same regs to bf16 ap for PV MFMA.
// Wave w: k-strip [512w,512w+512), PV d-tile [16w,16w+16). XCD swizzle 3072=8*384.
__global__ __launch_bounds__(256)
void attn_flash(const __hip_bfloat16* __restrict__ Qb,
                const __hip_bfloat16* __restrict__ Kb,
                const __hip_bfloat16* __restrict__ Vt,
                const int* __restrict__ mask, const float* __restrict__ temp,
                float* __restrict__ attn, __hip_bfloat16* __restrict__ ctx)
{
    __shared__ float wsum[4][16];
    __shared__ float ftile[4][16][33];

    const int tid  = threadIdx.x;
    const int lane = tid & 63;
    const int w    = tid >> 6;
    const int l16  = lane & 15;
    const int lq   = lane >> 4;

    const int bid = blockIdx.x;
    const int lb  = (bid & 7) * 384 + (bid >> 3);
    const int nqt = SQ_ / QT;                  // 64
    const int qt  = lb % nqt;
    const int h   = (lb / nqt) % NH;
    const int b   = lb / (nqt * NH);
    const int q0  = qt * QT;

    const float factor = 0.125f / temp[0];

    const __hip_bfloat16* Qbase = Qb + (((size_t)b * NH + h) * SQ_ + q0) * HD;
    const __hip_bfloat16* Kbase = Kb + ((size_t)b * NH + h) * SK_ * HD;
    const __hip_bfloat16* Vbase = Vt + ((size_t)b * NH + h) * HD * SK_;
    const int* mbase = mask + b * SK_;

    const bf16x8 a0 = *(const bf16x8*)&Qbase[(size_t)l16 * HD + lq * 8];
    const bf16x8 a1 = *(const bf16x8*)&Qbase[(size_t)l16 * HD + 32 + lq * 8];

    const int kw = w * 512;

    // ---- sweep 1: QK^T + exp -> packed bf16 p in registers, row sums ----
    unsigned int pk[64];                       // [t][r>>1], static-indexed (unrolled)
    float ssum[4] = {0.f, 0.f, 0.f, 0.f};
#pragma unroll
    for (int t = 0; t < 32; ++t) {
        const int k0 = kw + t * 16;
        const __hip_bfloat16* Krow = &Kbase[(size_t)(k0 + l16) * HD];
        bf16x8 b0 = *(const bf16x8*)&Krow[lq * 8];
        bf16x8 b1 = *(const bf16x8*)&Krow[32 + lq * 8];
        f32x4 acc = {};
        acc = mfma16(a0, b0, acc);
        acc = mfma16(a1, b1, acc);
        const bool live = mbase[k0 + l16] != 0;
        float e[4];
#pragma unroll
        for (int r = 0; r < 4; ++r) {
            e[r] = live ? __expf(acc[r] * factor) : 0.f;
            ssum[r] += e[r];
        }
#pragma unroll
        for (int hh = 0; hh < 2; ++hh) {
            const unsigned short u0 = __builtin_bit_cast(unsigned short, (__bf16)e[2 * hh]);
            const unsigned short u1 = __builtin_bit_cast(unsigned short, (__bf16)e[2 * hh + 1]);
            pk[t * 2 + hh] = (unsigned int)u0 | ((unsigned int)u1 << 16);
        }
    }
#pragma unroll
    for (int r = 0; r < 4; ++r)
#pragma unroll
        for (int off = 1; off < 16; off <<= 1)
            ssum[r] += __shfl_xor(ssum[r], off, 64);
    if (l16 == 0) {
#pragma unroll
        for (int r = 0; r < 4; ++r) wsum[w][lq * 4 + r] = ssum[r];
    }
    __syncthreads();
    float inv[4];
#pragma unroll
    for (int r = 0; r < 4; ++r) {
        const int row = lq * 4 + r;
        inv[r] = 1.f / (wsum[0][row] + wsum[1][row] + wsum[2][row] + wsum[3][row]);
    }

    // ---- sweep 2: normalize -> ftile; coalesced attn write + PV every 2 tiles ----
    f32x4 pv = {};
    float* abase = attn + ((size_t)((b * NH + h) * SQ_) + q0) * SK_;
#pragma unroll
    for (int t = 0; t < 32; ++t) {
        const int colb = (t & 1) * 16 + l16;
#pragma unroll
        for (int r = 0; r < 4; ++r) {
            const __bf16 pb = __builtin_bit_cast(
                __bf16, (unsigned short)(pk[t * 2 + (r >> 1)] >> (16 * (r & 1))));
            ftile[w][lq * 4 + r][colb] = (float)pb * inv[r];
        }
        if (t & 1) {
            const float4 f0 = *(const float4*)&ftile[w][l16][lq * 8];
            const float4 f1 = *(const float4*)&ftile[w][l16][lq * 8 + 4];
            float* dst = &abase[(size_t)l16 * SK_ + kw + (t - 1) * 16 + lq * 8];
            *(float4*)dst       = f0;
            *(float4*)(dst + 4) = f1;
            bf16x8 ap;
            ap[0] = (__bf16)f0.x; ap[1] = (__bf16)f0.y;
            ap[2] = (__bf16)f0.z; ap[3] = (__bf16)f0.w;
            ap[4] = (__bf16)f1.x; ap[5] = (__bf16)f1.y;
            ap[6] = (__bf16)f1.z; ap[7] = (__bf16)f1.w;
            const bf16x8 bp = *(const bf16x8*)&Vbase[(size_t)(w * 16 + l16) * SK_
                                                     + (kw + (t - 1) * 16) + lq * 8];
            pv = mfma16(ap, bp, pv);
        }
    }
#pragma unroll
    for (int r = 0; r < 4; ++r) {
        const int row = lq * 4 + r;
        ctx[((size_t)(b * SQ_) + q0 + row) * DM + h * HD + w * 16 + l16] =
            __float2bfloat16(pv[r]);
    }
}

// ---------------- in-place LayerNorm on d_out rows ----------------
__global__ __launch_bounds__(256)
void ln_kernel(float* __restrict__ x, const float* __restrict__ gamma,
               const float* __restrict__ beta)
{
    __shared__ float rb[8];
    const int row = blockIdx.x;
    const int tid = threadIdx.x;
    float v[3];
    float s = 0.f;
#pragma unroll
    for (int i = 0; i < 3; ++i) {
        v[i] = x[(size_t)row * DM + tid + i * 256];
        s += v[i];
    }
    s = blksum(s, rb, tid);
    const float mean = s * (1.0f / DM);
    float s2 = 0.f;
#pragma unroll
    for (int i = 0; i < 3; ++i) {
        const float d = v[i] - mean;
        s2 += d * d;
    }
    s2 = blksum(s2, rb, tid);
    const float rstd = rsqrtf(s2 * (1.0f / DM) + 1e-5f);
#pragma unroll
    for (int i = 0; i < 3; ++i) {
        const int c = tid + i * 256;
        x[(size_t)row * DM + c] = gamma[c] * (v[i] - mean) * rstd + beta[c];
    }
}

extern "C" void kernel_launch(void* const* d_in, const int* in_sizes, int n_in,
                              void* d_out, int out_size, void* d_ws, size_t ws_size,
                              hipStream_t stream)
{
    const float* query = (const float*)d_in[0];
    const float* key   = (const float*)d_in[1];
    const float* value = (const float*)d_in[2];
    const int*   mask  = (const int*)d_in[3];
    const float* Wq    = (const float*)d_in[4];
    const float* Wk    = (const float*)d_in[5];
    const float* Wv    = (const float*)d_in[6];
    const float* Wo    = (const float*)d_in[7];
    const float* bo    = (const float*)d_in[8];
    const float* gamma = (const float*)d_in[9];
    const float* beta  = (const float*)d_in[10];
    const float* temp  = (const float*)d_in[11];

    float* out  = (float*)d_out;                          // [B,SQ,DM]
    float* attn = out + (size_t)B_ * SQ_ * DM;            // [B,NH,SQ,SK] fp32

    __hip_bfloat16* Qb = (__hip_bfloat16*)d_ws;           // [B,NH,SQ,HD]
    __hip_bfloat16* Kb = Qb + (size_t)B_ * NH * SQ_ * HD; // [B,NH,SK,HD]
    __hip_bfloat16* Vt = Kb + (size_t)B_ * NH * SK_ * HD; // [B,NH,HD,SK]
    // C-region: 4 weight transposes + bf16 ctx
    __hip_bfloat16* Cb  = Vt + (size_t)B_ * NH * SK_ * HD;
    __hip_bfloat16* Wqt = Cb;
    __hip_bfloat16* Wkt = Wqt + (size_t)DM * DM;
    __hip_bfloat16* Wvt = Wkt + (size_t)DM * DM;
    __hip_bfloat16* Wot = Wvt + (size_t)DM * DM;
    __hip_bfloat16* ctxb = Wot + (size_t)DM * DM;         // [B,SQ,DM] bf16
    // cast scratch (bf16 copies of q/k/v)
    __hip_bfloat16* Shq = ctxb + (size_t)B_ * SQ_ * DM;
    __hip_bfloat16* Shk = Shq + (size_t)B_ * SQ_ * DM;
    __hip_bfloat16* Shv = Shk + (size_t)B_ * SK_ * DM;

    dim3 blk(256);
    hipLaunchKernelGGL(transpose_cast4, dim3(12, 12, 4), blk, 0, stream,
                       Wq, Wk, Wv, Wo, Wqt, Wkt, Wvt, Wot);

    hipLaunchKernelGGL(cast3_bf16, dim3(15360), blk, 0, stream,
                       query, key, value, Shq, Shk, Shv);

    hipLaunchKernelGGL(gemm_qkv, dim3(3840), blk, 0, stream,
                       Shq, Shk, Shv, Wqt, Wkt, Wvt, Qb, Kb, Vt);

    hipLaunchKernelGGL(attn_flash, dim3(B_ * NH * (SQ_ / QT)), blk, 0, stream,
                       Qb, Kb, Vt, mask, temp, attn, ctxb);

    hipLaunchKernelGGL(gemm_o, dim3(768), blk, 0, stream,
                       ctxb, Wot, out, bo, query);

    hipLaunchKernelGGL(ln_kernel, dim3(B_ * SQ_), blk, 0, stream, out, gamma, beta);
}